// Round 1
// baseline (1687.222 us; speedup 1.0000x reference)
//
#include <hip/hip_runtime.h>
#include <math.h>

#define N_NODES 100000
#define E_EDGES 1600000
#define D_IN 64
#define HID1 128
#define HID2 64
#define ATT 32

__device__ inline unsigned f2o(float f){ unsigned u = __float_as_uint(f); return (u >> 31) ? ~u : (u | 0x80000000u); }
__device__ inline float o2f(unsigned u){ return (u >> 31) ? __uint_as_float(u & 0x7fffffffu) : __uint_as_float(~u); }

__global__ void k_init(float* pooled, float* Z, unsigned* maxu){
    int t = threadIdx.x;
    if (t < 64) pooled[t] = 0.f;
    if (t == 64) *Z = 0.f;
    if (t == 65) *maxu = f2o(-INFINITY);
}

// edge-parallel: 4 edges per 256-thread block, 64 lanes per edge
__global__ void k_agg1(const float* __restrict__ x, const int* __restrict__ src, const int* __restrict__ dst,
                       float* __restrict__ agg, float* __restrict__ deg){
    int lane = threadIdx.x & 63;
    int row  = threadIdx.x >> 6;
    int e = blockIdx.x * 4 + row;
    if (e >= E_EDGES) return;
    int s = src[e], d = dst[e];
    float v = x[(size_t)s * D_IN + lane];
    atomicAdd(&agg[(size_t)d * D_IN + lane], v);
    if (lane == 0) atomicAdd(&deg[d], 1.0f);
}

// h1 = relu(agg1/deg @ W1_l + x @ W1_r + b1); 2 nodes per 256-thread block
__global__ void k_h1(const float* __restrict__ x, const float* __restrict__ agg, const float* __restrict__ deg,
                     const float* __restrict__ W1l, const float* __restrict__ W1r, const float* __restrict__ b1,
                     float* __restrict__ h1){
    __shared__ float sx[2][64], sa[2][64];
    int half = threadIdx.x >> 7;      // 0..1
    int j    = threadIdx.x & 127;     // 0..127
    int n = blockIdx.x * 2 + half;
    if (n < N_NODES && j < 64){
        sx[half][j] = x[(size_t)n * 64 + j];
        sa[half][j] = agg[(size_t)n * 64 + j];
    }
    __syncthreads();
    if (n >= N_NODES) return;
    float inv = 1.0f / fmaxf(deg[n], 1.0f);
    float suml = 0.f, sumr = b1[j];
    #pragma unroll
    for (int k = 0; k < 64; k++){
        suml += sa[half][k] * W1l[k * 128 + j];
        sumr += sx[half][k] * W1r[k * 128 + j];
    }
    h1[(size_t)n * 128 + j] = fmaxf(sumr + suml * inv, 0.f);
}

// edge-parallel: 2 edges per 256-thread block, 128 lanes per edge
__global__ void k_agg2(const float* __restrict__ h1, const int* __restrict__ src, const int* __restrict__ dst,
                       float* __restrict__ agg2){
    int lane = threadIdx.x & 127;
    int row  = threadIdx.x >> 7;
    int e = blockIdx.x * 2 + row;
    if (e >= E_EDGES) return;
    int s = src[e], d = dst[e];
    atomicAdd(&agg2[(size_t)d * HID1 + lane], h1[(size_t)s * HID1 + lane]);
}

// h2 = relu(agg2/deg @ W2_l + h1 @ W2_r + b2); scores=tanh(h2@Wa+ba); wlogit = scores.ctx + x[:,63]*0.4
// one node per 64-thread block
__global__ void k_h2(const float* __restrict__ x, const float* __restrict__ h1, const float* __restrict__ agg2,
                     const float* __restrict__ deg,
                     const float* __restrict__ W2l, const float* __restrict__ W2r, const float* __restrict__ b2,
                     const float* __restrict__ Wa, const float* __restrict__ ba, const float* __restrict__ ctx,
                     float* __restrict__ h2, float* __restrict__ wlogit){
    __shared__ float sh[128], sg[128], sh2[64];
    int n = blockIdx.x;
    int t = threadIdx.x; // 0..63
    sh[t]      = h1[(size_t)n * 128 + t];
    sh[t + 64] = h1[(size_t)n * 128 + 64 + t];
    sg[t]      = agg2[(size_t)n * 128 + t];
    sg[t + 64] = agg2[(size_t)n * 128 + 64 + t];
    __syncthreads();
    float inv = 1.0f / fmaxf(deg[n], 1.0f);
    float suml = 0.f, sumr = b2[t];
    #pragma unroll 8
    for (int k = 0; k < 128; k++){
        suml += sg[k] * W2l[k * 64 + t];
        sumr += sh[k] * W2r[k * 64 + t];
    }
    float v = fmaxf(sumr + suml * inv, 0.f);
    sh2[t] = v;
    h2[(size_t)n * 64 + t] = v;
    __syncthreads();
    float pa = 0.f;
    if (t < ATT){
        float s = ba[t];
        #pragma unroll 8
        for (int j = 0; j < 64; j++) s += sh2[j] * Wa[j * ATT + t];
        pa = tanhf(s) * ctx[t];
    }
    #pragma unroll
    for (int off = 32; off >= 1; off >>= 1) pa += __shfl_down(pa, off, 64);
    if (t == 0) wlogit[n] = pa + x[(size_t)n * 64 + 63] * 0.4f;
}

__global__ void k_max(const float* __restrict__ wlogit, unsigned* __restrict__ maxu){
    float m = -INFINITY;
    for (size_t i = (size_t)blockIdx.x * blockDim.x + threadIdx.x; i < N_NODES; i += (size_t)gridDim.x * blockDim.x)
        m = fmaxf(m, wlogit[i]);
    #pragma unroll
    for (int off = 32; off >= 1; off >>= 1) m = fmaxf(m, __shfl_down(m, off, 64));
    __shared__ float sm[4];
    if ((threadIdx.x & 63) == 0) sm[threadIdx.x >> 6] = m;
    __syncthreads();
    if (threadIdx.x == 0){
        float mm = fmaxf(fmaxf(sm[0], sm[1]), fmaxf(sm[2], sm[3]));
        atomicMax(maxu, f2o(mm));
    }
}

// pooled[j] = sum_n h2[n][j]*exp(w[n]-max); Z = sum_n exp(w[n]-max)
__global__ void k_pool(const float* __restrict__ h2, const float* __restrict__ wlogit,
                       const unsigned* __restrict__ maxu, float* __restrict__ pooled, float* __restrict__ Z){
    float mv = o2f(*maxu);
    int lane = threadIdx.x & 63;
    int row  = threadIdx.x >> 6; // 0..3
    float pacc = 0.f, zacc = 0.f;
    for (size_t n = (size_t)blockIdx.x * 4 + row; n < N_NODES; n += (size_t)gridDim.x * 4){
        float e = expf(wlogit[n] - mv);
        pacc += h2[n * 64 + lane] * e;
        zacc += e;
    }
    __shared__ float sp[4][64];
    sp[row][lane] = pacc;
    __syncthreads();
    if (threadIdx.x < 64){
        float s = sp[0][threadIdx.x] + sp[1][threadIdx.x] + sp[2][threadIdx.x] + sp[3][threadIdx.x];
        atomicAdd(&pooled[threadIdx.x], s);
    }
    if (lane == 0) atomicAdd(Z, zacc);
}

__global__ void k_final(const float* __restrict__ pooled, const float* __restrict__ Z,
                        const float* __restrict__ Wc1, const float* __restrict__ bc1,
                        const float* __restrict__ Wc2, const float* __restrict__ bc2,
                        float* __restrict__ out){
    __shared__ float sp[64], sz[32];
    int t = threadIdx.x;
    float scale = 1.0f / ((*Z) * (float)N_NODES);
    sp[t] = pooled[t] * scale;
    __syncthreads();
    if (t < 32){
        float s = bc1[t];
        #pragma unroll 8
        for (int j = 0; j < 64; j++) s += sp[j] * Wc1[j * 32 + t];
        sz[t] = fmaxf(s, 0.f);
    }
    __syncthreads();
    if (t == 0){
        float s = bc2[0];
        #pragma unroll
        for (int i = 0; i < 32; i++) s += sz[i] * Wc2[i];
        out[0] = 1.0f / (1.0f + expf(-s));
    }
}

extern "C" void kernel_launch(void* const* d_in, const int* in_sizes, int n_in,
                              void* d_out, int out_size, void* d_ws, size_t ws_size,
                              hipStream_t stream) {
    const float* x   = (const float*)d_in[0];
    const int*   ei  = (const int*)d_in[1];
    const int*   src = ei;
    const int*   dst = ei + E_EDGES;
    const float* W1l = (const float*)d_in[2];
    const float* W1r = (const float*)d_in[3];
    const float* b1  = (const float*)d_in[4];
    const float* W2l = (const float*)d_in[5];
    const float* W2r = (const float*)d_in[6];
    const float* b2  = (const float*)d_in[7];
    const float* Wa  = (const float*)d_in[8];
    const float* ba  = (const float*)d_in[9];
    const float* ctx = (const float*)d_in[10];
    const float* Wc1 = (const float*)d_in[11];
    const float* bc1 = (const float*)d_in[12];
    const float* Wc2 = (const float*)d_in[13];
    const float* bc2 = (const float*)d_in[14];

    float* ws     = (float*)d_ws;
    float* deg    = ws;                                   // N
    float* bufA   = ws + N_NODES;                         // N*64  (agg1, reused as h2)
    float* h1     = bufA + (size_t)N_NODES * 64;          // N*128
    float* agg2   = h1 + (size_t)N_NODES * 128;           // N*128
    float* wlogit = agg2 + (size_t)N_NODES * 128;         // N
    float* pooled = wlogit + N_NODES;                     // 64
    float* Zp     = pooled + 64;                          // 1
    unsigned* maxu = (unsigned*)(Zp + 1);                 // 1

    hipMemsetAsync(deg, 0, N_NODES * sizeof(float), stream);
    hipMemsetAsync(bufA, 0, (size_t)N_NODES * 64 * sizeof(float), stream);
    hipMemsetAsync(agg2, 0, (size_t)N_NODES * 128 * sizeof(float), stream);
    k_init<<<1, 128, 0, stream>>>(pooled, Zp, maxu);

    k_agg1<<<(E_EDGES + 3) / 4, 256, 0, stream>>>(x, src, dst, bufA, deg);
    k_h1<<<(N_NODES + 1) / 2, 256, 0, stream>>>(x, bufA, deg, W1l, W1r, b1, h1);
    k_agg2<<<(E_EDGES + 1) / 2, 256, 0, stream>>>(h1, src, dst, agg2);
    k_h2<<<N_NODES, 64, 0, stream>>>(x, h1, agg2, deg, W2l, W2r, b2, Wa, ba, ctx, bufA, wlogit);
    k_max<<<512, 256, 0, stream>>>(wlogit, maxu);
    k_pool<<<1024, 256, 0, stream>>>(bufA, wlogit, maxu, pooled, Zp);
    k_final<<<1, 64, 0, stream>>>(pooled, Zp, Wc1, bc1, Wc2, bc2, (float*)d_out);
}

// Round 2
// 920.248 us; speedup vs baseline: 1.8334x; 1.8334x over previous
//
#include <hip/hip_runtime.h>
#include <math.h>

#define N_NODES 100000
#define E_EDGES 1600000
#define D_IN 64
#define HID1 128
#define HID2 64
#define ATT 32
#define CHUNK 1024
#define NB_SCAN ((N_NODES + CHUNK - 1) / CHUNK)   // 98

__device__ inline unsigned f2o(float f){ unsigned u = __float_as_uint(f); return (u >> 31) ? ~u : (u | 0x80000000u); }
__device__ inline float o2f(unsigned u){ return (u >> 31) ? __uint_as_float(u & 0x7fffffffu) : __uint_as_float(~u); }

__global__ void k_init(float* pooled, float* Z, unsigned* maxu){
    int t = threadIdx.x;
    if (t < 64) pooled[t] = 0.f;
    if (t == 64) *Z = 0.f;
    if (t == 65) *maxu = f2o(-INFINITY);
}

__global__ void k_hist(const int* __restrict__ dst, int* __restrict__ cnt){
    int i = blockIdx.x * blockDim.x + threadIdx.x;
    if (i < E_EDGES) atomicAdd(&cnt[dst[i]], 1);
}

__global__ void k_scan1(const int* __restrict__ cnt, int* __restrict__ bsum){
    int base = blockIdx.x * CHUNK + threadIdx.x * 4;
    int s = 0;
    #pragma unroll
    for (int k = 0; k < 4; k++){ int i = base + k; if (i < N_NODES) s += cnt[i]; }
    #pragma unroll
    for (int off = 32; off >= 1; off >>= 1) s += __shfl_down(s, off, 64);
    __shared__ int sm[4];
    if ((threadIdx.x & 63) == 0) sm[threadIdx.x >> 6] = s;
    __syncthreads();
    if (threadIdx.x == 0) bsum[blockIdx.x] = sm[0] + sm[1] + sm[2] + sm[3];
}

__global__ void k_scan2(const int* __restrict__ bsum, int* __restrict__ bscan){
    __shared__ int sb[NB_SCAN];
    int t = threadIdx.x;
    if (t < NB_SCAN) sb[t] = bsum[t];
    __syncthreads();
    if (t == 0){ int run = 0; for (int i = 0; i < NB_SCAN; i++){ int v = sb[i]; sb[i] = run; run += v; } }
    __syncthreads();
    if (t < NB_SCAN) bscan[t] = sb[t];
}

__global__ void k_scan3(const int* __restrict__ cnt, const int* __restrict__ bscan,
                        int* __restrict__ rowptr, int* __restrict__ rowcur){
    __shared__ int ts[256];
    int t = threadIdx.x;
    int base = blockIdx.x * CHUNK + t * 4;
    int v[4]; int s = 0;
    #pragma unroll
    for (int k = 0; k < 4; k++){ int i = base + k; v[k] = (i < N_NODES) ? cnt[i] : 0; s += v[k]; }
    ts[t] = s;
    __syncthreads();
    int total = s;
    for (int off = 1; off < 256; off <<= 1){
        int a = 0;
        if (t >= off) a = ts[t - off];
        __syncthreads();
        ts[t] += a;
        __syncthreads();
    }
    int excl = ts[t] - total + bscan[blockIdx.x];
    #pragma unroll
    for (int k = 0; k < 4; k++){
        int i = base + k;
        if (i < N_NODES){ rowptr[i] = excl; rowcur[i] = excl; excl += v[k]; }
    }
}

__global__ void k_scatter(const int* __restrict__ src, const int* __restrict__ dst,
                          int* __restrict__ rowcur, int* __restrict__ ssrc){
    int i = blockIdx.x * blockDim.x + threadIdx.x;
    if (i < E_EDGES){
        int d = dst[i];
        int pos = atomicAdd(&rowcur[d], 1);
        ssrc[pos] = src[i];
    }
}

// pull-aggregate x (mean) + layer1: h1 = relu(mean1 @ W1_l + x @ W1_r + b1)
// 4 nodes per 256-thread block, one wave (64 lanes) per node
__global__ void k_fused1(const float* __restrict__ x, const int* __restrict__ ssrc,
                         const int* __restrict__ rowptr, const int* __restrict__ cnt,
                         const float* __restrict__ W1l, const float* __restrict__ W1r,
                         const float* __restrict__ b1, float* __restrict__ h1){
    __shared__ float smean[4][64], sx[4][64];
    int g = threadIdx.x >> 6, lane = threadIdx.x & 63;
    int n = blockIdx.x * 4 + g;
    int beg = rowptr[n], c = cnt[n];
    int e = beg, end = beg + c;
    float acc = 0.f;
    for (; e + 4 <= end; e += 4){
        int s0 = ssrc[e], s1 = ssrc[e+1], s2 = ssrc[e+2], s3 = ssrc[e+3];
        acc += x[(size_t)s0*64 + lane] + x[(size_t)s1*64 + lane]
             + x[(size_t)s2*64 + lane] + x[(size_t)s3*64 + lane];
    }
    for (; e < end; e++) acc += x[(size_t)ssrc[e]*64 + lane];
    float inv = 1.f / fmaxf((float)c, 1.f);
    smean[g][lane] = acc * inv;
    sx[g][lane] = x[(size_t)n*64 + lane];
    __syncthreads();
    float a0 = b1[lane], a1 = b1[lane + 64];
    #pragma unroll 8
    for (int k = 0; k < 64; k++){
        float m = smean[g][k], xv = sx[g][k];
        a0 += m * W1l[k*128 + lane]      + xv * W1r[k*128 + lane];
        a1 += m * W1l[k*128 + lane + 64] + xv * W1r[k*128 + lane + 64];
    }
    h1[(size_t)n*128 + lane]      = fmaxf(a0, 0.f);
    h1[(size_t)n*128 + lane + 64] = fmaxf(a1, 0.f);
}

// pull-aggregate h1 (mean) + layer2 + attention logit
// 2 nodes per 256-thread block, 128 lanes per node
__global__ void k_fused2(const float* __restrict__ x, const float* __restrict__ h1,
                         const int* __restrict__ ssrc, const int* __restrict__ rowptr,
                         const int* __restrict__ cnt,
                         const float* __restrict__ W2l, const float* __restrict__ W2r,
                         const float* __restrict__ b2,
                         const float* __restrict__ Wa, const float* __restrict__ ba,
                         const float* __restrict__ ctx,
                         float* __restrict__ h2, float* __restrict__ wlogit){
    __shared__ float smean[2][128], sh[2][128], sh2[2][64];
    int g = threadIdx.x >> 7, t = threadIdx.x & 127;
    int n = blockIdx.x * 2 + g;
    int beg = rowptr[n], c = cnt[n];
    int e = beg, end = beg + c;
    float acc = 0.f;
    for (; e + 4 <= end; e += 4){
        int s0 = ssrc[e], s1 = ssrc[e+1], s2 = ssrc[e+2], s3 = ssrc[e+3];
        acc += h1[(size_t)s0*128 + t] + h1[(size_t)s1*128 + t]
             + h1[(size_t)s2*128 + t] + h1[(size_t)s3*128 + t];
    }
    for (; e < end; e++) acc += h1[(size_t)ssrc[e]*128 + t];
    float inv = 1.f / fmaxf((float)c, 1.f);
    smean[g][t] = acc * inv;
    sh[g][t] = h1[(size_t)n*128 + t];
    __syncthreads();
    if (t < 64){
        float suml = 0.f, sumr = b2[t];
        #pragma unroll 8
        for (int k = 0; k < 128; k++){
            suml += smean[g][k] * W2l[k*64 + t];
            sumr += sh[g][k]    * W2r[k*64 + t];
        }
        float v = fmaxf(suml + sumr, 0.f);
        sh2[g][t] = v;
        h2[(size_t)n*64 + t] = v;
    }
    __syncthreads();
    if (t < 64){   // first wave of this node's pair
        float pa = 0.f;
        if (t < ATT){
            float s = ba[t];
            #pragma unroll 8
            for (int j = 0; j < 64; j++) s += sh2[g][j] * Wa[j*ATT + t];
            pa = tanhf(s) * ctx[t];
        }
        #pragma unroll
        for (int off = 32; off >= 1; off >>= 1) pa += __shfl_down(pa, off, 64);
        if (t == 0) wlogit[n] = pa + x[(size_t)n*64 + 63] * 0.4f;
    }
}

__global__ void k_max(const float* __restrict__ wlogit, unsigned* __restrict__ maxu){
    float m = -INFINITY;
    for (size_t i = (size_t)blockIdx.x * blockDim.x + threadIdx.x; i < N_NODES; i += (size_t)gridDim.x * blockDim.x)
        m = fmaxf(m, wlogit[i]);
    #pragma unroll
    for (int off = 32; off >= 1; off >>= 1) m = fmaxf(m, __shfl_down(m, off, 64));
    __shared__ float sm[4];
    if ((threadIdx.x & 63) == 0) sm[threadIdx.x >> 6] = m;
    __syncthreads();
    if (threadIdx.x == 0){
        float mm = fmaxf(fmaxf(sm[0], sm[1]), fmaxf(sm[2], sm[3]));
        atomicMax(maxu, f2o(mm));
    }
}

__global__ void k_pool(const float* __restrict__ h2, const float* __restrict__ wlogit,
                       const unsigned* __restrict__ maxu, float* __restrict__ pooled, float* __restrict__ Z){
    float mv = o2f(*maxu);
    int lane = threadIdx.x & 63;
    int row  = threadIdx.x >> 6;
    float pacc = 0.f, zacc = 0.f;
    for (size_t n = (size_t)blockIdx.x * 4 + row; n < N_NODES; n += (size_t)gridDim.x * 4){
        float e = expf(wlogit[n] - mv);
        pacc += h2[n * 64 + lane] * e;
        zacc += e;
    }
    __shared__ float sp[4][64];
    sp[row][lane] = pacc;
    __syncthreads();
    if (threadIdx.x < 64){
        float s = sp[0][threadIdx.x] + sp[1][threadIdx.x] + sp[2][threadIdx.x] + sp[3][threadIdx.x];
        atomicAdd(&pooled[threadIdx.x], s);
    }
    if (lane == 0) atomicAdd(Z, zacc);
}

__global__ void k_final(const float* __restrict__ pooled, const float* __restrict__ Z,
                        const float* __restrict__ Wc1, const float* __restrict__ bc1,
                        const float* __restrict__ Wc2, const float* __restrict__ bc2,
                        float* __restrict__ out){
    __shared__ float sp[64], sz[32];
    int t = threadIdx.x;
    float scale = 1.0f / ((*Z) * (float)N_NODES);
    sp[t] = pooled[t] * scale;
    __syncthreads();
    if (t < 32){
        float s = bc1[t];
        #pragma unroll 8
        for (int j = 0; j < 64; j++) s += sp[j] * Wc1[j * 32 + t];
        sz[t] = fmaxf(s, 0.f);
    }
    __syncthreads();
    if (t == 0){
        float s = bc2[0];
        #pragma unroll
        for (int i = 0; i < 32; i++) s += sz[i] * Wc2[i];
        out[0] = 1.0f / (1.0f + expf(-s));
    }
}

extern "C" void kernel_launch(void* const* d_in, const int* in_sizes, int n_in,
                              void* d_out, int out_size, void* d_ws, size_t ws_size,
                              hipStream_t stream) {
    const float* x   = (const float*)d_in[0];
    const int*   ei  = (const int*)d_in[1];
    const int*   src = ei;
    const int*   dst = ei + E_EDGES;
    const float* W1l = (const float*)d_in[2];
    const float* W1r = (const float*)d_in[3];
    const float* b1  = (const float*)d_in[4];
    const float* W2l = (const float*)d_in[5];
    const float* W2r = (const float*)d_in[6];
    const float* b2  = (const float*)d_in[7];
    const float* Wa  = (const float*)d_in[8];
    const float* ba  = (const float*)d_in[9];
    const float* ctx = (const float*)d_in[10];
    const float* Wc1 = (const float*)d_in[11];
    const float* bc1 = (const float*)d_in[12];
    const float* Wc2 = (const float*)d_in[13];
    const float* bc2 = (const float*)d_in[14];

    char* p = (char*)d_ws;
    int* cnt    = (int*)p;                 p += (size_t)N_NODES * 4;
    int* rowptr = (int*)p;                 p += (size_t)N_NODES * 4;
    int* rowcur = (int*)p;                 p += (size_t)N_NODES * 4;
    int* bsum   = (int*)p;                 p += 128 * 4;
    int* bscan  = (int*)p;                 p += 128 * 4;
    int* ssrc   = (int*)p;                 p += (size_t)E_EDGES * 4;
    float* h1     = (float*)p;             p += (size_t)N_NODES * 128 * 4;
    float* h2     = (float*)p;             p += (size_t)N_NODES * 64 * 4;
    float* wlogit = (float*)p;             p += (size_t)N_NODES * 4;
    float* pooled = (float*)p;             p += 64 * 4;
    float* Zp     = (float*)p;             p += 4;
    unsigned* maxu = (unsigned*)p;

    hipMemsetAsync(cnt, 0, (size_t)N_NODES * 4, stream);
    k_init<<<1, 128, 0, stream>>>(pooled, Zp, maxu);

    k_hist<<<(E_EDGES + 255) / 256, 256, 0, stream>>>(dst, cnt);
    k_scan1<<<NB_SCAN, 256, 0, stream>>>(cnt, bsum);
    k_scan2<<<1, 128, 0, stream>>>(bsum, bscan);
    k_scan3<<<NB_SCAN, 256, 0, stream>>>(cnt, bscan, rowptr, rowcur);
    k_scatter<<<(E_EDGES + 255) / 256, 256, 0, stream>>>(src, dst, rowcur, ssrc);

    k_fused1<<<N_NODES / 4, 256, 0, stream>>>(x, ssrc, rowptr, cnt, W1l, W1r, b1, h1);
    k_fused2<<<N_NODES / 2, 256, 0, stream>>>(x, h1, ssrc, rowptr, cnt, W2l, W2r, b2, Wa, ba, ctx, h2, wlogit);

    k_max<<<512, 256, 0, stream>>>(wlogit, maxu);
    k_pool<<<1024, 256, 0, stream>>>(h2, wlogit, maxu, pooled, Zp);
    k_final<<<1, 64, 0, stream>>>(pooled, Zp, Wc1, bc1, Wc2, bc2, (float*)d_out);
}